// Round 3
// baseline (279.934 us; speedup 1.0000x reference)
//
#include <hip/hip_runtime.h>
#include <hip/hip_bf16.h>

#define TPB 256

typedef _Float16 f16;
typedef f16 f16x8 __attribute__((ext_vector_type(8)));
typedef f16 f16x2 __attribute__((ext_vector_type(2)));
typedef float f32x16 __attribute__((ext_vector_type(16)));
typedef unsigned int uint;

union F16x8U { f16x8 v; uint4 q; };

__device__ __forceinline__ float elu_f(float z) {
    return z > 0.f ? z : __expf(z) - 1.f;
}

// ---------------------------------------------------------------------------
// K1: hist[r][f] = 1e-4 * sum_{o<band} Xs[tril_col(r,o)][f]
// ---------------------------------------------------------------------------
__global__ void hist_kernel(const float* __restrict__ Xs, const int* __restrict__ tril,
                            float* __restrict__ hist, int S, int band, int F) {
    int gid = blockIdx.x * blockDim.x + threadIdx.x;
    if (gid >= S * F) return;
    int r = gid / F;
    int f = gid - r * F;
    const int* tre = tril + (size_t)r * band * 2;
    float acc = 0.f;
    for (int o = 0; o < band; ++o) {
        int c = tre[o * 2 + 1];
        acc += Xs[(size_t)c * F + f];
    }
    hist[gid] = acc * 1e-4f;
}

// ---------------------------------------------------------------------------
// K2 prep: all transposed f16 weight splits.
//   W1bT_hi/lo[n][k]  (256x64)  from W1 rows 640..703
//   W1sT_hi[n][k]     (256x64)  from sum of the PW 64-row blocks of W1
//   W2T_hi/lo[n][k]   (256x256) from W2 transposed
// ---------------------------------------------------------------------------
__global__ void prep_kernel(const float* __restrict__ W1, const float* __restrict__ W2,
                            int PW,
                            f16* __restrict__ W1bT_hi, f16* __restrict__ W1bT_lo,
                            f16* __restrict__ W1sT_hi,
                            f16* __restrict__ W2T_hi, f16* __restrict__ W2T_lo) {
    int t = blockIdx.x * blockDim.x + threadIdx.x;
    if (t < 16384) {
        int n = t >> 6, k = t & 63;
        float x = W1[(size_t)(PW * 64 + k) * 256 + n];
        f16 h = (f16)x;
        W1bT_hi[t] = h;
        W1bT_lo[t] = (f16)(x - (float)h);
    } else if (t < 32768) {
        int t1 = t - 16384;
        int n = t1 >> 6, k = t1 & 63;
        float s = 0.f;
        for (int p = 0; p < PW; ++p) s += W1[(size_t)(p * 64 + k) * 256 + n];
        W1sT_hi[t1] = (f16)s;
    } else if (t < 98304) {
        int t2 = t - 32768;
        int n = t2 >> 8, k = t2 & 255;
        float x = W2[(size_t)k * 256 + n];
        f16 h = (f16)x;
        W2T_hi[t2] = h;
        W2T_lo[t2] = (f16)(x - (float)h);
    }
}

// ---------------------------------------------------------------------------
// K3: Ahist = hist @ W1sum + b1 via transposed MFMA (1-term f16; Ahist's
// contribution to z1 is ~500x smaller than the dispF term, error negligible).
// Block: 4 waves, 128 sessions; wave w owns n-tiles {2w,2w+1} x 4 s-tiles.
// ---------------------------------------------------------------------------
__global__ __launch_bounds__(TPB, 2) void ahist_mfma_kernel(
    const float* __restrict__ hist, const f16* __restrict__ W1sT_hi,
    const float* __restrict__ b1, float* __restrict__ Ahist, int S)
{
    const int tid = threadIdx.x;
    const int w = tid >> 6, l = tid & 63, lr = l & 31, hh = l >> 5;
    const int SB = blockIdx.x * 128;
    const int nt0 = 2 * w;

    #pragma unroll
    for (int st = 0; st < 4; ++st) {
        int sg = SB + st * 32 + lr;
        int sgc = sg <= S - 1 ? sg : S - 1;
        F16x8U Bh[4];
        #pragma unroll
        for (int ks = 0; ks < 4; ++ks) {
            const float* hp = hist + (size_t)sgc * 64 + ks * 16 + 8 * hh;
            float4 x0 = *(const float4*)hp;
            float4 x1 = *(const float4*)(hp + 4);
            Bh[ks].v[0] = (f16)x0.x; Bh[ks].v[1] = (f16)x0.y;
            Bh[ks].v[2] = (f16)x0.z; Bh[ks].v[3] = (f16)x0.w;
            Bh[ks].v[4] = (f16)x1.x; Bh[ks].v[5] = (f16)x1.y;
            Bh[ks].v[6] = (f16)x1.z; Bh[ks].v[7] = (f16)x1.w;
        }
        #pragma unroll
        for (int jn = 0; jn < 2; ++jn) {
            int nt = nt0 + jn;
            f32x16 acc;
            #pragma unroll
            for (int rq = 0; rq < 4; ++rq) {
                float4 bq = *(const float4*)&b1[nt * 32 + rq * 8 + 4 * hh];
                acc[rq * 4 + 0] = bq.x; acc[rq * 4 + 1] = bq.y;
                acc[rq * 4 + 2] = bq.z; acc[rq * 4 + 3] = bq.w;
            }
            const f16* ah = W1sT_hi + (size_t)(nt * 32 + lr) * 64 + 8 * hh;
            #pragma unroll
            for (int ks = 0; ks < 4; ++ks) {
                f16x8 Ah = *(const f16x8*)(ah + ks * 16);
                acc = __builtin_amdgcn_mfma_f32_32x32x16_f16(Ah, Bh[ks].v, acc, 0, 0, 0);
            }
            if (sg < S) {
                float* op = Ahist + (size_t)sg * 256 + nt * 32 + 4 * hh;
                #pragma unroll
                for (int rq = 0; rq < 4; ++rq) {
                    *(float4*)(op + rq * 8) = make_float4(
                        acc[rq * 4 + 0], acc[rq * 4 + 1], acc[rq * 4 + 2], acc[rq * 4 + 3]);
                }
            }
        }
    }
}

// ---------------------------------------------------------------------------
// K4: fused MLP, frag-exchange design.
// Layer1 (transposed): z1^T = W1b(hi+lo) x dispF_hi + Ahist  -> C: lane=col r.
// elu -> pack f16 pairs -> half-exchange (shfl_xor 32) -> layer-2 B-frags,
// stored in LDS [st][kt][lane] (own-slot 16B: conflict-free, no unpack).
// Layer2: A = W2T hi/lo from global (per-wave n2 slice), B = frags from LDS.
// Layer3: fold elu(z2)*W3 per lane, hh-shuffle, tiny LDS reduce over waves.
// ---------------------------------------------------------------------------
__global__ __launch_bounds__(TPB, 2) void mlp3_kernel(
    const float* __restrict__ dispF, const float* __restrict__ Ahist,
    const f16* __restrict__ W1bT_hi, const f16* __restrict__ W1bT_lo,
    const f16* __restrict__ W2T_hi, const f16* __restrict__ W2T_lo,
    const float* __restrict__ b2, const float* __restrict__ W3,
    const float* __restrict__ b3, float* __restrict__ u,
    int ND, int per, float inv_per)
{
    __shared__ uint4 frag[4][16][64];   // 64KB frag-exchange buffer

    const int tid = threadIdx.x;
    const int w = tid >> 6, l = tid & 63, lr = l & 31, hh = l >> 5;
    const int RB = blockIdx.x * 128;
    const int nt0 = 2 * w;

    // ---------------- Phase 1: layer 1 (n-tiles 2w,2w+1 x 4 row-tiles) -----
    #pragma unroll
    for (int st = 0; st < 4; ++st) {
        int rg = RB + st * 32 + lr;
        int rgc = rg <= ND - 1 ? rg : ND - 1;
        int srow = (int)((float)rgc * inv_per);
        srow += ((srow + 1) * per <= rgc) ? 1 : 0;
        const float* ap = Ahist + (size_t)srow * 256;

        F16x8U Dh[4];
        #pragma unroll
        for (int ks = 0; ks < 4; ++ks) {
            const float* dp = dispF + (size_t)rgc * 64 + ks * 16 + 8 * hh;
            float4 x0 = *(const float4*)dp;
            float4 x1 = *(const float4*)(dp + 4);
            Dh[ks].v[0] = (f16)x0.x; Dh[ks].v[1] = (f16)x0.y;
            Dh[ks].v[2] = (f16)x0.z; Dh[ks].v[3] = (f16)x0.w;
            Dh[ks].v[4] = (f16)x1.x; Dh[ks].v[5] = (f16)x1.y;
            Dh[ks].v[6] = (f16)x1.z; Dh[ks].v[7] = (f16)x1.w;
        }
        #pragma unroll
        for (int jn = 0; jn < 2; ++jn) {
            int nt = nt0 + jn;
            f32x16 acc;
            #pragma unroll
            for (int rq = 0; rq < 4; ++rq) {
                float4 av = *(const float4*)&ap[nt * 32 + rq * 8 + 4 * hh];
                acc[rq * 4 + 0] = av.x; acc[rq * 4 + 1] = av.y;
                acc[rq * 4 + 2] = av.z; acc[rq * 4 + 3] = av.w;
            }
            const f16* a1h = W1bT_hi + (size_t)(nt * 32 + lr) * 64 + 8 * hh;
            const f16* a1l = W1bT_lo + (size_t)(nt * 32 + lr) * 64 + 8 * hh;
            #pragma unroll
            for (int ks = 0; ks < 4; ++ks) {
                f16x8 Ah = *(const f16x8*)(a1h + ks * 16);
                f16x8 Al = *(const f16x8*)(a1l + ks * 16);
                acc = __builtin_amdgcn_mfma_f32_32x32x16_f16(Ah, Dh[ks].v, acc, 0, 0, 0);
                acc = __builtin_amdgcn_mfma_f32_32x32x16_f16(Al, Dh[ks].v, acc, 0, 0, 0);
            }
            // elu + f16 pack (pairs along n1) + half-exchange -> B-frags
            uint p[4][2];
            #pragma unroll
            for (int rq = 0; rq < 4; ++rq) {
                #pragma unroll
                for (int jj = 0; jj < 2; ++jj) {
                    float a = elu_f(acc[rq * 4 + 2 * jj]);
                    float b = elu_f(acc[rq * 4 + 2 * jj + 1]);
                    f16x2 hp; hp[0] = (f16)a; hp[1] = (f16)b;
                    p[rq][jj] = __builtin_bit_cast(uint, hp);
                }
            }
            #pragma unroll
            for (int c = 0; c < 2; ++c) {
                uint s0 = hh ? p[2 * c][0] : p[2 * c + 1][0];
                uint s1 = hh ? p[2 * c][1] : p[2 * c + 1][1];
                uint r0 = __shfl_xor(s0, 32, 64);
                uint r1 = __shfl_xor(s1, 32, 64);
                uint4 B;
                B.x = hh ? r0 : p[2 * c][0];
                B.y = hh ? r1 : p[2 * c][1];
                B.z = hh ? p[2 * c + 1][0] : r0;
                B.w = hh ? p[2 * c + 1][1] : r1;
                frag[st][2 * nt + c][l] = B;
            }
        }
    }
    __syncthreads();

    // ---------------- Phase 2: layer 2 (n2 slice {2w,2w+1}, all 128 rows) --
    f32x16 acc2[4][2];
    #pragma unroll
    for (int j = 0; j < 2; ++j) {
        #pragma unroll
        for (int rq = 0; rq < 4; ++rq) {
            float4 bq = *(const float4*)&b2[(nt0 + j) * 32 + rq * 8 + 4 * hh];
            #pragma unroll
            for (int st = 0; st < 4; ++st) {
                acc2[st][j][rq * 4 + 0] = bq.x; acc2[st][j][rq * 4 + 1] = bq.y;
                acc2[st][j][rq * 4 + 2] = bq.z; acc2[st][j][rq * 4 + 3] = bq.w;
            }
        }
    }
    const f16* w2h0 = W2T_hi + (size_t)(nt0 * 32 + lr) * 256 + 8 * hh;
    const f16* w2l0 = W2T_lo + (size_t)(nt0 * 32 + lr) * 256 + 8 * hh;
    const f16* w2h1 = W2T_hi + (size_t)((nt0 + 1) * 32 + lr) * 256 + 8 * hh;
    const f16* w2l1 = W2T_lo + (size_t)((nt0 + 1) * 32 + lr) * 256 + 8 * hh;

    #pragma unroll
    for (int kt = 0; kt < 16; ++kt) {
        f16x8 A0h = *(const f16x8*)(w2h0 + kt * 16);
        f16x8 A0l = *(const f16x8*)(w2l0 + kt * 16);
        f16x8 A1h = *(const f16x8*)(w2h1 + kt * 16);
        f16x8 A1l = *(const f16x8*)(w2l1 + kt * 16);
        #pragma unroll
        for (int st = 0; st < 4; ++st) {
            F16x8U B; B.q = frag[st][kt][l];
            acc2[st][0] = __builtin_amdgcn_mfma_f32_32x32x16_f16(A0h, B.v, acc2[st][0], 0, 0, 0);
            acc2[st][0] = __builtin_amdgcn_mfma_f32_32x32x16_f16(A0l, B.v, acc2[st][0], 0, 0, 0);
            acc2[st][1] = __builtin_amdgcn_mfma_f32_32x32x16_f16(A1h, B.v, acc2[st][1], 0, 0, 0);
            acc2[st][1] = __builtin_amdgcn_mfma_f32_32x32x16_f16(A1l, B.v, acc2[st][1], 0, 0, 0);
        }
    }

    // ---------------- Phase 3: layer-3 fold + reduce -----------------------
    float up[4] = {0.f, 0.f, 0.f, 0.f};
    #pragma unroll
    for (int j = 0; j < 2; ++j) {
        #pragma unroll
        for (int rq = 0; rq < 4; ++rq) {
            float4 wq = *(const float4*)&W3[(nt0 + j) * 32 + rq * 8 + 4 * hh];
            #pragma unroll
            for (int st = 0; st < 4; ++st) {
                up[st] += elu_f(acc2[st][j][rq * 4 + 0]) * wq.x
                        + elu_f(acc2[st][j][rq * 4 + 1]) * wq.y
                        + elu_f(acc2[st][j][rq * 4 + 2]) * wq.z
                        + elu_f(acc2[st][j][rq * 4 + 3]) * wq.w;
            }
        }
    }
    #pragma unroll
    for (int st = 0; st < 4; ++st) up[st] += __shfl_xor(up[st], 32, 64);

    __syncthreads();   // frag reads done; reuse LDS as reduce buffer
    float* pb = (float*)frag;
    if (hh == 0) {
        #pragma unroll
        for (int st = 0; st < 4; ++st) pb[(w * 4 + st) * 32 + lr] = up[st];
    }
    __syncthreads();
    if (tid < 128) {
        float v = pb[tid] + pb[128 + tid] + pb[256 + tid] + pb[384 + tid];
        int rg = RB + tid;
        if (rg < ND) u[rg] = v + b3[0];
    }
}

// ---------------------------------------------------------------------------
// K5: per-session loss + argmax/top-2 precision counts
// ---------------------------------------------------------------------------
template <int PER>
__global__ void session_kernel(const float* __restrict__ u, const int* __restrict__ clickSub,
                               const int* __restrict__ clickIdx, const int* __restrict__ dispIdx,
                               float* __restrict__ pLoss, int* __restrict__ pP1,
                               int* __restrict__ pP2, int S) {
    int s = blockIdx.x * blockDim.x + threadIdx.x;
    float lossv = 0.f; int p1 = 0, p2 = 0;
    if (s < S) {
        int base = s * PER;
        float ev[PER]; int it[PER];
        float sum_exp = 0.f;
        #pragma unroll
        for (int i = 0; i < PER; ++i) {
            float uu = u[base + i];
            ev[i] = expf(uu);
            sum_exp += ev[i];
            it[i] = dispIdx[(size_t)(base + i) * 2 + 1];
        }
        int crow = clickSub[s];
        lossv = -u[crow] + logf(sum_exp + 1.f);

        float bestv = -1.f; int besti = 0x7FFFFFFF;
        float secv = -1.f;  int seci = 0x7FFFFFFF;
        int ndist = 0;
        #pragma unroll
        for (int i = 0; i < PER; ++i) {
            bool first = true; float tot = 0.f;
            #pragma unroll
            for (int j = 0; j < PER; ++j) {
                if (it[j] == it[i]) { tot += ev[j]; if (j < i) first = false; }
            }
            if (first) {
                ndist++;
                if (tot > bestv || (tot == bestv && it[i] < besti)) {
                    secv = bestv; seci = besti;
                    bestv = tot;  besti = it[i];
                } else if (tot > secv || (tot == secv && it[i] < seci)) {
                    secv = tot; seci = it[i];
                }
            }
        }
        if (ndist < 2) seci = (besti == 0) ? 1 : 0;
        int citem = clickIdx[s * 2 + 1];
        p1 = (citem == besti) ? 1 : 0;
        p2 = (citem == besti || citem == seci) ? 1 : 0;
    }
    __shared__ float rf[TPB]; __shared__ int r1[TPB]; __shared__ int r2[TPB];
    int t = threadIdx.x;
    rf[t] = lossv; r1[t] = p1; r2[t] = p2;
    __syncthreads();
    for (int off = TPB / 2; off > 0; off >>= 1) {
        if (t < off) { rf[t] += rf[t + off]; r1[t] += r1[t + off]; r2[t] += r2[t + off]; }
        __syncthreads();
    }
    if (t == 0) { pLoss[blockIdx.x] = rf[0]; pP1[blockIdx.x] = r1[0]; pP2[blockIdx.x] = r2[0]; }
}

// ---------------------------------------------------------------------------
// K6: reduce block partials, emit the 7 scalar outputs.
// ---------------------------------------------------------------------------
__global__ void finalize_kernel(const float* __restrict__ pLoss, const int* __restrict__ pP1,
                                const int* __restrict__ pP2, int nb, float event_cnt,
                                float* __restrict__ out) {
    __shared__ float sf[TPB]; __shared__ int s1[TPB]; __shared__ int s2[TPB];
    int t = threadIdx.x;
    float lf = 0.f; int a1 = 0, a2 = 0;
    for (int i = t; i < nb; i += TPB) { lf += pLoss[i]; a1 += pP1[i]; a2 += pP2[i]; }
    sf[t] = lf; s1[t] = a1; s2[t] = a2;
    __syncthreads();
    for (int off = TPB / 2; off > 0; off >>= 1) {
        if (t < off) { sf[t] += sf[t + off]; s1[t] += s1[t + off]; s2[t] += s2[t + off]; }
        __syncthreads();
    }
    if (t == 0) {
        float ls = sf[0];
        float p1 = (float)s1[0];
        float p2 = (float)s2[0];
        out[0] = ls / event_cnt;
        out[1] = p1 / event_cnt;
        out[2] = p2 / event_cnt;
        out[3] = ls;
        out[4] = p1;
        out[5] = p2;
        out[6] = event_cnt;
    }
}

// ---------------------------------------------------------------------------
extern "C" void kernel_launch(void* const* d_in, const int* in_sizes, int n_in,
                              void* d_out, int out_size, void* d_ws, size_t ws_size,
                              hipStream_t stream) {
    const float* dispF    = (const float*)d_in[0];
    const float* Xs       = (const float*)d_in[1];
    const float* W1       = (const float*)d_in[2];
    const float* b1       = (const float*)d_in[3];
    const float* W2       = (const float*)d_in[4];
    const float* b2       = (const float*)d_in[5];
    const float* W3       = (const float*)d_in[6];
    const float* b3       = (const float*)d_in[7];
    const int*   tril     = (const int*)d_in[8];
    const int*   clickSub = (const int*)d_in[11];
    const int*   clickIdx = (const int*)d_in[12];
    const int*   dispIdx  = (const int*)d_in[13];

    const int S    = in_sizes[11];
    const int ND   = in_sizes[10];
    const int F    = in_sizes[1] / S;            // 64
    const int H    = in_sizes[3];                // 256
    const int NT   = in_sizes[9];
    const int BAND = NT / S;                     // 20
    const int PW   = in_sizes[2] / (F * H) - 1;  // 10
    const int per  = ND / S;                     // 10

    float* ws    = (float*)d_ws;
    float* hist  = ws;                                   // S*F
    float* Ahist = hist + (size_t)S * F;                 // S*H
    float* u     = Ahist + (size_t)S * H;                // ND (+pad)
    const int nb5 = (S + TPB - 1) / TPB;
    float* pLoss = u + ((size_t)ND + 128);               // nb5
    int*   pP1   = (int*)(pLoss + nb5);
    int*   pP2   = pP1 + nb5;
    size_t f32_used = (size_t)(pP2 + nb5 - (int*)ws);
    f32_used = (f32_used + 3) & ~(size_t)3;              // 16B align
    f16* W1bT_hi = (f16*)(ws + f32_used);                // 256*64
    f16* W1bT_lo = W1bT_hi + 16384;
    f16* W1sT_hi = W1bT_lo + 16384;                      // 256*64
    f16* W2T_hi  = W1sT_hi + 16384;                      // 256*256
    f16* W2T_lo  = W2T_hi + 65536;

    hist_kernel<<<(S * F + TPB - 1) / TPB, TPB, 0, stream>>>(Xs, tril, hist, S, BAND, F);
    prep_kernel<<<384, TPB, 0, stream>>>(W1, W2, PW, W1bT_hi, W1bT_lo, W1sT_hi, W2T_hi, W2T_lo);
    ahist_mfma_kernel<<<(S + 127) / 128, TPB, 0, stream>>>(hist, W1sT_hi, b1, Ahist, S);
    mlp3_kernel<<<(ND + 127) / 128, TPB, 0, stream>>>(
        dispF, Ahist, W1bT_hi, W1bT_lo, W2T_hi, W2T_lo, b2, W3, b3, u,
        ND, per, 1.0f / (float)per);
    session_kernel<10><<<nb5, TPB, 0, stream>>>(u, clickSub, clickIdx, dispIdx, pLoss, pP1, pP2, S);
    finalize_kernel<<<1, TPB, 0, stream>>>(pLoss, pP1, pP2, nb5, (float)S, (float*)d_out);
}

// Round 4
// 259.379 us; speedup vs baseline: 1.0792x; 1.0792x over previous
//
#include <hip/hip_runtime.h>
#include <hip/hip_bf16.h>

#define TPB 256

typedef _Float16 f16;
typedef f16 f16x8 __attribute__((ext_vector_type(8)));
typedef f16 f16x2 __attribute__((ext_vector_type(2)));
typedef float f32x16 __attribute__((ext_vector_type(16)));
typedef unsigned int uint;

union F16x8U { f16x8 v; uint4 q; };

__device__ __forceinline__ float elu_f(float z) {
    return z > 0.f ? z : __expf(z) - 1.f;
}

// ---------------------------------------------------------------------------
// K1: hist[r][f] = 1e-4 * sum_{o<band} Xs[tril_col(r,o)][f]
// ---------------------------------------------------------------------------
__global__ void hist_kernel(const float* __restrict__ Xs, const int* __restrict__ tril,
                            float* __restrict__ hist, int S, int band, int F) {
    int gid = blockIdx.x * blockDim.x + threadIdx.x;
    if (gid >= S * F) return;
    int r = gid / F;
    int f = gid - r * F;
    const int* tre = tril + (size_t)r * band * 2;
    float acc = 0.f;
    for (int o = 0; o < band; ++o) {
        int c = tre[o * 2 + 1];
        acc += Xs[(size_t)c * F + f];
    }
    hist[gid] = acc * 1e-4f;
}

// ---------------------------------------------------------------------------
// K2 prep: transposed f16 weight splits.
// ---------------------------------------------------------------------------
__global__ void prep_kernel(const float* __restrict__ W1, const float* __restrict__ W2,
                            int PW,
                            f16* __restrict__ W1bT_hi, f16* __restrict__ W1bT_lo,
                            f16* __restrict__ W1sT_hi,
                            f16* __restrict__ W2T_hi, f16* __restrict__ W2T_lo) {
    int t = blockIdx.x * blockDim.x + threadIdx.x;
    if (t < 16384) {
        int n = t >> 6, k = t & 63;
        float x = W1[(size_t)(PW * 64 + k) * 256 + n];
        f16 h = (f16)x;
        W1bT_hi[t] = h;
        W1bT_lo[t] = (f16)(x - (float)h);
    } else if (t < 32768) {
        int t1 = t - 16384;
        int n = t1 >> 6, k = t1 & 63;
        float s = 0.f;
        for (int p = 0; p < PW; ++p) s += W1[(size_t)(p * 64 + k) * 256 + n];
        W1sT_hi[t1] = (f16)s;
    } else if (t < 98304) {
        int t2 = t - 32768;
        int n = t2 >> 8, k = t2 & 255;
        float x = W2[(size_t)k * 256 + n];
        f16 h = (f16)x;
        W2T_hi[t2] = h;
        W2T_lo[t2] = (f16)(x - (float)h);
    }
}

// ---------------------------------------------------------------------------
// K3: Ahist = hist @ W1sum + b1 via transposed MFMA (1-term f16).
// ---------------------------------------------------------------------------
__global__ __launch_bounds__(TPB, 2) void ahist_mfma_kernel(
    const float* __restrict__ hist, const f16* __restrict__ W1sT_hi,
    const float* __restrict__ b1, float* __restrict__ Ahist, int S)
{
    const int tid = threadIdx.x;
    const int w = tid >> 6, l = tid & 63, lr = l & 31, hh = l >> 5;
    const int SB = blockIdx.x * 128;
    const int nt0 = 2 * w;

    #pragma unroll
    for (int st = 0; st < 4; ++st) {
        int sg = SB + st * 32 + lr;
        int sgc = sg <= S - 1 ? sg : S - 1;
        F16x8U Bh[4];
        #pragma unroll
        for (int ks = 0; ks < 4; ++ks) {
            const float* hp = hist + (size_t)sgc * 64 + ks * 16 + 8 * hh;
            float4 x0 = *(const float4*)hp;
            float4 x1 = *(const float4*)(hp + 4);
            Bh[ks].v[0] = (f16)x0.x; Bh[ks].v[1] = (f16)x0.y;
            Bh[ks].v[2] = (f16)x0.z; Bh[ks].v[3] = (f16)x0.w;
            Bh[ks].v[4] = (f16)x1.x; Bh[ks].v[5] = (f16)x1.y;
            Bh[ks].v[6] = (f16)x1.z; Bh[ks].v[7] = (f16)x1.w;
        }
        #pragma unroll
        for (int jn = 0; jn < 2; ++jn) {
            int nt = nt0 + jn;
            f32x16 acc;
            #pragma unroll
            for (int rq = 0; rq < 4; ++rq) {
                float4 bq = *(const float4*)&b1[nt * 32 + rq * 8 + 4 * hh];
                acc[rq * 4 + 0] = bq.x; acc[rq * 4 + 1] = bq.y;
                acc[rq * 4 + 2] = bq.z; acc[rq * 4 + 3] = bq.w;
            }
            const f16* ah = W1sT_hi + (size_t)(nt * 32 + lr) * 64 + 8 * hh;
            #pragma unroll
            for (int ks = 0; ks < 4; ++ks) {
                f16x8 Ah = *(const f16x8*)(ah + ks * 16);
                acc = __builtin_amdgcn_mfma_f32_32x32x16_f16(Ah, Bh[ks].v, acc, 0, 0, 0);
            }
            if (sg < S) {
                float* op = Ahist + (size_t)sg * 256 + nt * 32 + 4 * hh;
                #pragma unroll
                for (int rq = 0; rq < 4; ++rq) {
                    *(float4*)(op + rq * 8) = make_float4(
                        acc[rq * 4 + 0], acc[rq * 4 + 1], acc[rq * 4 + 2], acc[rq * 4 + 3]);
                }
            }
        }
    }
}

// ---------------------------------------------------------------------------
// K4: fused MLP, frag-exchange, 8 waves x 128 rows, 1 n-tile per wave.
// 64KB LDS + <=128 VGPR -> 2 blocks/CU, 16 waves/CU (50% occupancy).
// ---------------------------------------------------------------------------
__global__ __launch_bounds__(512, 4) void mlp4_kernel(
    const float* __restrict__ dispF, const float* __restrict__ Ahist,
    const f16* __restrict__ W1bT_hi, const f16* __restrict__ W1bT_lo,
    const f16* __restrict__ W2T_hi, const f16* __restrict__ W2T_lo,
    const float* __restrict__ b2, const float* __restrict__ W3,
    const float* __restrict__ b3, float* __restrict__ u,
    int ND, int per, float inv_per)
{
    __shared__ uint4 frag[4][16][64];   // 64KB frag-exchange buffer

    const int tid = threadIdx.x;
    const int w = tid >> 6, l = tid & 63, lr = l & 31, hh = l >> 5;
    const int RB = blockIdx.x * 128;
    const int nt = w;                    // wave's n-tile (0..7)

    // hoisted layer-1 A-frags (W1b rows for this wave's 32 output cols)
    const f16* a1h = W1bT_hi + (size_t)(nt * 32 + lr) * 64 + 8 * hh;
    const f16* a1l = W1bT_lo + (size_t)(nt * 32 + lr) * 64 + 8 * hh;
    f16x8 A1h[4], A1l[4];
    #pragma unroll
    for (int ks = 0; ks < 4; ++ks) {
        A1h[ks] = *(const f16x8*)(a1h + ks * 16);
        A1l[ks] = *(const f16x8*)(a1l + ks * 16);
    }

    // ---------------- Phase 1: layer 1 ------------------------------------
    #pragma unroll
    for (int st = 0; st < 4; ++st) {
        int rg = RB + st * 32 + lr;
        int rgc = rg <= ND - 1 ? rg : ND - 1;
        int srow = (int)((float)rgc * inv_per);
        srow += ((srow + 1) * per <= rgc) ? 1 : 0;
        const float* ap = Ahist + (size_t)srow * 256;

        F16x8U Dh[4];
        #pragma unroll
        for (int ks = 0; ks < 4; ++ks) {
            const float* dp = dispF + (size_t)rgc * 64 + ks * 16 + 8 * hh;
            float4 x0 = *(const float4*)dp;
            float4 x1 = *(const float4*)(dp + 4);
            Dh[ks].v[0] = (f16)x0.x; Dh[ks].v[1] = (f16)x0.y;
            Dh[ks].v[2] = (f16)x0.z; Dh[ks].v[3] = (f16)x0.w;
            Dh[ks].v[4] = (f16)x1.x; Dh[ks].v[5] = (f16)x1.y;
            Dh[ks].v[6] = (f16)x1.z; Dh[ks].v[7] = (f16)x1.w;
        }

        f32x16 acc;
        #pragma unroll
        for (int rq = 0; rq < 4; ++rq) {
            float4 av = *(const float4*)&ap[nt * 32 + rq * 8 + 4 * hh];
            acc[rq * 4 + 0] = av.x; acc[rq * 4 + 1] = av.y;
            acc[rq * 4 + 2] = av.z; acc[rq * 4 + 3] = av.w;
        }
        #pragma unroll
        for (int ks = 0; ks < 4; ++ks) {
            acc = __builtin_amdgcn_mfma_f32_32x32x16_f16(A1h[ks], Dh[ks].v, acc, 0, 0, 0);
            acc = __builtin_amdgcn_mfma_f32_32x32x16_f16(A1l[ks], Dh[ks].v, acc, 0, 0, 0);
        }

        // elu + f16 pack (pairs along n1) + half-exchange -> layer-2 B-frags
        uint p[4][2];
        #pragma unroll
        for (int rq = 0; rq < 4; ++rq) {
            #pragma unroll
            for (int jj = 0; jj < 2; ++jj) {
                float a = elu_f(acc[rq * 4 + 2 * jj]);
                float b = elu_f(acc[rq * 4 + 2 * jj + 1]);
                f16x2 hp; hp[0] = (f16)a; hp[1] = (f16)b;
                p[rq][jj] = __builtin_bit_cast(uint, hp);
            }
        }
        #pragma unroll
        for (int c = 0; c < 2; ++c) {
            uint s0 = hh ? p[2 * c][0] : p[2 * c + 1][0];
            uint s1 = hh ? p[2 * c][1] : p[2 * c + 1][1];
            uint r0 = __shfl_xor(s0, 32, 64);
            uint r1 = __shfl_xor(s1, 32, 64);
            uint4 B;
            B.x = hh ? r0 : p[2 * c][0];
            B.y = hh ? r1 : p[2 * c][1];
            B.z = hh ? p[2 * c + 1][0] : r0;
            B.w = hh ? p[2 * c + 1][1] : r1;
            frag[st][2 * nt + c][l] = B;
        }
    }
    __syncthreads();

    // ---------------- Phase 2: layer 2 (wave's 32 n2 cols, all 128 rows) --
    f32x16 acc2[4];
    #pragma unroll
    for (int rq = 0; rq < 4; ++rq) {
        float4 bq = *(const float4*)&b2[nt * 32 + rq * 8 + 4 * hh];
        #pragma unroll
        for (int st = 0; st < 4; ++st) {
            acc2[st][rq * 4 + 0] = bq.x; acc2[st][rq * 4 + 1] = bq.y;
            acc2[st][rq * 4 + 2] = bq.z; acc2[st][rq * 4 + 3] = bq.w;
        }
    }
    const f16* w2h = W2T_hi + (size_t)(nt * 32 + lr) * 256 + 8 * hh;
    const f16* w2l = W2T_lo + (size_t)(nt * 32 + lr) * 256 + 8 * hh;

    #pragma unroll 4
    for (int kt = 0; kt < 16; ++kt) {
        f16x8 Ah = *(const f16x8*)(w2h + kt * 16);
        f16x8 Al = *(const f16x8*)(w2l + kt * 16);
        #pragma unroll
        for (int st = 0; st < 4; ++st) {
            F16x8U B; B.q = frag[st][kt][l];
            acc2[st] = __builtin_amdgcn_mfma_f32_32x32x16_f16(Ah, B.v, acc2[st], 0, 0, 0);
            acc2[st] = __builtin_amdgcn_mfma_f32_32x32x16_f16(Al, B.v, acc2[st], 0, 0, 0);
        }
    }

    // ---------------- Phase 3: layer-3 fold + cross-wave reduce ------------
    float up[4] = {0.f, 0.f, 0.f, 0.f};
    #pragma unroll
    for (int rq = 0; rq < 4; ++rq) {
        float4 wq = *(const float4*)&W3[nt * 32 + rq * 8 + 4 * hh];
        #pragma unroll
        for (int st = 0; st < 4; ++st) {
            up[st] += elu_f(acc2[st][rq * 4 + 0]) * wq.x
                    + elu_f(acc2[st][rq * 4 + 1]) * wq.y
                    + elu_f(acc2[st][rq * 4 + 2]) * wq.z
                    + elu_f(acc2[st][rq * 4 + 3]) * wq.w;
        }
    }
    #pragma unroll
    for (int st = 0; st < 4; ++st) up[st] += __shfl_xor(up[st], 32, 64);

    __syncthreads();   // frag reads done; reuse LDS as reduce buffer
    float* pb = (float*)frag;
    if (hh == 0) {
        #pragma unroll
        for (int st = 0; st < 4; ++st) pb[(w * 4 + st) * 32 + lr] = up[st];
    }
    __syncthreads();
    if (tid < 128) {
        int st = tid >> 5, lrr = tid & 31;
        float v = 0.f;
        #pragma unroll
        for (int w2 = 0; w2 < 8; ++w2) v += pb[(w2 * 4 + st) * 32 + lrr];
        int rg = RB + tid;
        if (rg < ND) u[rg] = v + b3[0];
    }
}

// ---------------------------------------------------------------------------
// K5: per-session loss + argmax/top-2 precision counts
// ---------------------------------------------------------------------------
template <int PER>
__global__ void session_kernel(const float* __restrict__ u, const int* __restrict__ clickSub,
                               const int* __restrict__ clickIdx, const int* __restrict__ dispIdx,
                               float* __restrict__ pLoss, int* __restrict__ pP1,
                               int* __restrict__ pP2, int S) {
    int s = blockIdx.x * blockDim.x + threadIdx.x;
    float lossv = 0.f; int p1 = 0, p2 = 0;
    if (s < S) {
        int base = s * PER;
        float ev[PER]; int it[PER];
        float sum_exp = 0.f;
        #pragma unroll
        for (int i = 0; i < PER; ++i) {
            float uu = u[base + i];
            ev[i] = expf(uu);
            sum_exp += ev[i];
            it[i] = dispIdx[(size_t)(base + i) * 2 + 1];
        }
        int crow = clickSub[s];
        lossv = -u[crow] + logf(sum_exp + 1.f);

        float bestv = -1.f; int besti = 0x7FFFFFFF;
        float secv = -1.f;  int seci = 0x7FFFFFFF;
        int ndist = 0;
        #pragma unroll
        for (int i = 0; i < PER; ++i) {
            bool first = true; float tot = 0.f;
            #pragma unroll
            for (int j = 0; j < PER; ++j) {
                if (it[j] == it[i]) { tot += ev[j]; if (j < i) first = false; }
            }
            if (first) {
                ndist++;
                if (tot > bestv || (tot == bestv && it[i] < besti)) {
                    secv = bestv; seci = besti;
                    bestv = tot;  besti = it[i];
                } else if (tot > secv || (tot == secv && it[i] < seci)) {
                    secv = tot; seci = it[i];
                }
            }
        }
        if (ndist < 2) seci = (besti == 0) ? 1 : 0;
        int citem = clickIdx[s * 2 + 1];
        p1 = (citem == besti) ? 1 : 0;
        p2 = (citem == besti || citem == seci) ? 1 : 0;
    }
    __shared__ float rf[TPB]; __shared__ int r1[TPB]; __shared__ int r2[TPB];
    int t = threadIdx.x;
    rf[t] = lossv; r1[t] = p1; r2[t] = p2;
    __syncthreads();
    for (int off = TPB / 2; off > 0; off >>= 1) {
        if (t < off) { rf[t] += rf[t + off]; r1[t] += r1[t + off]; r2[t] += r2[t + off]; }
        __syncthreads();
    }
    if (t == 0) { pLoss[blockIdx.x] = rf[0]; pP1[blockIdx.x] = r1[0]; pP2[blockIdx.x] = r2[0]; }
}

// ---------------------------------------------------------------------------
// K6: reduce block partials, emit the 7 scalar outputs.
// ---------------------------------------------------------------------------
__global__ void finalize_kernel(const float* __restrict__ pLoss, const int* __restrict__ pP1,
                                const int* __restrict__ pP2, int nb, float event_cnt,
                                float* __restrict__ out) {
    __shared__ float sf[TPB]; __shared__ int s1[TPB]; __shared__ int s2[TPB];
    int t = threadIdx.x;
    float lf = 0.f; int a1 = 0, a2 = 0;
    for (int i = t; i < nb; i += TPB) { lf += pLoss[i]; a1 += pP1[i]; a2 += pP2[i]; }
    sf[t] = lf; s1[t] = a1; s2[t] = a2;
    __syncthreads();
    for (int off = TPB / 2; off > 0; off >>= 1) {
        if (t < off) { sf[t] += sf[t + off]; s1[t] += s1[t + off]; s2[t] += s2[t + off]; }
        __syncthreads();
    }
    if (t == 0) {
        float ls = sf[0];
        float p1 = (float)s1[0];
        float p2 = (float)s2[0];
        out[0] = ls / event_cnt;
        out[1] = p1 / event_cnt;
        out[2] = p2 / event_cnt;
        out[3] = ls;
        out[4] = p1;
        out[5] = p2;
        out[6] = event_cnt;
    }
}

// ---------------------------------------------------------------------------
extern "C" void kernel_launch(void* const* d_in, const int* in_sizes, int n_in,
                              void* d_out, int out_size, void* d_ws, size_t ws_size,
                              hipStream_t stream) {
    const float* dispF    = (const float*)d_in[0];
    const float* Xs       = (const float*)d_in[1];
    const float* W1       = (const float*)d_in[2];
    const float* b1       = (const float*)d_in[3];
    const float* W2       = (const float*)d_in[4];
    const float* b2       = (const float*)d_in[5];
    const float* W3       = (const float*)d_in[6];
    const float* b3       = (const float*)d_in[7];
    const int*   tril     = (const int*)d_in[8];
    const int*   clickSub = (const int*)d_in[11];
    const int*   clickIdx = (const int*)d_in[12];
    const int*   dispIdx  = (const int*)d_in[13];

    const int S    = in_sizes[11];
    const int ND   = in_sizes[10];
    const int F    = in_sizes[1] / S;            // 64
    const int H    = in_sizes[3];                // 256
    const int NT   = in_sizes[9];
    const int BAND = NT / S;                     // 20
    const int PW   = in_sizes[2] / (F * H) - 1;  // 10
    const int per  = ND / S;                     // 10

    float* ws    = (float*)d_ws;
    float* hist  = ws;                                   // S*F
    float* Ahist = hist + (size_t)S * F;                 // S*H
    float* u     = Ahist + (size_t)S * H;                // ND (+pad)
    const int nb5 = (S + TPB - 1) / TPB;
    float* pLoss = u + ((size_t)ND + 128);               // nb5
    int*   pP1   = (int*)(pLoss + nb5);
    int*   pP2   = pP1 + nb5;
    size_t f32_used = (size_t)(pP2 + nb5 - (int*)ws);
    f32_used = (f32_used + 3) & ~(size_t)3;              // 16B align
    f16* W1bT_hi = (f16*)(ws + f32_used);                // 256*64
    f16* W1bT_lo = W1bT_hi + 16384;
    f16* W1sT_hi = W1bT_lo + 16384;                      // 256*64
    f16* W2T_hi  = W1sT_hi + 16384;                      // 256*256
    f16* W2T_lo  = W2T_hi + 65536;

    hist_kernel<<<(S * F + TPB - 1) / TPB, TPB, 0, stream>>>(Xs, tril, hist, S, BAND, F);
    prep_kernel<<<384, TPB, 0, stream>>>(W1, W2, PW, W1bT_hi, W1bT_lo, W1sT_hi, W2T_hi, W2T_lo);
    ahist_mfma_kernel<<<(S + 127) / 128, TPB, 0, stream>>>(hist, W1sT_hi, b1, Ahist, S);
    mlp4_kernel<<<(ND + 127) / 128, 512, 0, stream>>>(
        dispF, Ahist, W1bT_hi, W1bT_lo, W2T_hi, W2T_lo, b2, W3, b3, u,
        ND, per, 1.0f / (float)per);
    session_kernel<10><<<nb5, TPB, 0, stream>>>(u, clickSub, clickIdx, dispIdx, pLoss, pP1, pP2, S);
    finalize_kernel<<<1, TPB, 0, stream>>>(pLoss, pP1, pP2, nb5, (float)S, (float*)d_out);
}

// Round 5
// 249.419 us; speedup vs baseline: 1.1223x; 1.0399x over previous
//
#include <hip/hip_runtime.h>
#include <hip/hip_bf16.h>

#define TPB 256

typedef _Float16 f16;
typedef f16 f16x8 __attribute__((ext_vector_type(8)));
typedef f16 f16x2 __attribute__((ext_vector_type(2)));
typedef float f32x16 __attribute__((ext_vector_type(16)));
typedef unsigned int uint;

union F16x8U { f16x8 v; uint4 q; };

__device__ __forceinline__ float elu_f(float z) {
    return z > 0.f ? z : __expf(z) - 1.f;
}

// ---------------------------------------------------------------------------
// K1: hist[r][f] = 1e-4 * sum_{o<band} Xs[tril_col(r,o)][f]
// ---------------------------------------------------------------------------
__global__ void hist_kernel(const float* __restrict__ Xs, const int* __restrict__ tril,
                            float* __restrict__ hist, int S, int band, int F) {
    int gid = blockIdx.x * blockDim.x + threadIdx.x;
    if (gid >= S * F) return;
    int r = gid / F;
    int f = gid - r * F;
    const int* tre = tril + (size_t)r * band * 2;
    float acc = 0.f;
    for (int o = 0; o < band; ++o) {
        int c = tre[o * 2 + 1];
        acc += Xs[(size_t)c * F + f];
    }
    hist[gid] = acc * 1e-4f;
}

// ---------------------------------------------------------------------------
// K2 prep: transposed f16 weight splits.
// ---------------------------------------------------------------------------
__global__ void prep_kernel(const float* __restrict__ W1, const float* __restrict__ W2,
                            int PW,
                            f16* __restrict__ W1bT_hi, f16* __restrict__ W1bT_lo,
                            f16* __restrict__ W1sT_hi,
                            f16* __restrict__ W2T_hi, f16* __restrict__ W2T_lo) {
    int t = blockIdx.x * blockDim.x + threadIdx.x;
    if (t < 16384) {
        int n = t >> 6, k = t & 63;
        float x = W1[(size_t)(PW * 64 + k) * 256 + n];
        f16 h = (f16)x;
        W1bT_hi[t] = h;
        W1bT_lo[t] = (f16)(x - (float)h);
    } else if (t < 32768) {
        int t1 = t - 16384;
        int n = t1 >> 6, k = t1 & 63;
        float s = 0.f;
        for (int p = 0; p < PW; ++p) s += W1[(size_t)(p * 64 + k) * 256 + n];
        W1sT_hi[t1] = (f16)s;
    } else if (t < 98304) {
        int t2 = t - 32768;
        int n = t2 >> 8, k = t2 & 255;
        float x = W2[(size_t)k * 256 + n];
        f16 h = (f16)x;
        W2T_hi[t2] = h;
        W2T_lo[t2] = (f16)(x - (float)h);
    }
}

// ---------------------------------------------------------------------------
// K2b: dispF -> f16 preconversion (removes cvt VALU + halves HBM in mlp).
// ---------------------------------------------------------------------------
__global__ void dispf16_kernel(const float* __restrict__ dispF,
                               f16* __restrict__ dispF16, int n8) {
    int stride = gridDim.x * blockDim.x;
    for (int i = blockIdx.x * blockDim.x + threadIdx.x; i < n8; i += stride) {
        float4 a = ((const float4*)dispF)[2 * i];
        float4 b = ((const float4*)dispF)[2 * i + 1];
        f16x8 o;
        o[0] = (f16)a.x; o[1] = (f16)a.y; o[2] = (f16)a.z; o[3] = (f16)a.w;
        o[4] = (f16)b.x; o[5] = (f16)b.y; o[6] = (f16)b.z; o[7] = (f16)b.w;
        ((f16x8*)dispF16)[i] = o;
    }
}

// ---------------------------------------------------------------------------
// K3: Ahist = hist @ W1sum + b1 via transposed MFMA (1-term f16).
// ---------------------------------------------------------------------------
__global__ __launch_bounds__(TPB, 2) void ahist_mfma_kernel(
    const float* __restrict__ hist, const f16* __restrict__ W1sT_hi,
    const float* __restrict__ b1, float* __restrict__ Ahist, int S)
{
    const int tid = threadIdx.x;
    const int w = tid >> 6, l = tid & 63, lr = l & 31, hh = l >> 5;
    const int SB = blockIdx.x * 128;
    const int nt0 = 2 * w;

    #pragma unroll
    for (int st = 0; st < 4; ++st) {
        int sg = SB + st * 32 + lr;
        int sgc = sg <= S - 1 ? sg : S - 1;
        F16x8U Bh[4];
        #pragma unroll
        for (int ks = 0; ks < 4; ++ks) {
            const float* hp = hist + (size_t)sgc * 64 + ks * 16 + 8 * hh;
            float4 x0 = *(const float4*)hp;
            float4 x1 = *(const float4*)(hp + 4);
            Bh[ks].v[0] = (f16)x0.x; Bh[ks].v[1] = (f16)x0.y;
            Bh[ks].v[2] = (f16)x0.z; Bh[ks].v[3] = (f16)x0.w;
            Bh[ks].v[4] = (f16)x1.x; Bh[ks].v[5] = (f16)x1.y;
            Bh[ks].v[6] = (f16)x1.z; Bh[ks].v[7] = (f16)x1.w;
        }
        #pragma unroll
        for (int jn = 0; jn < 2; ++jn) {
            int nt = nt0 + jn;
            f32x16 acc;
            #pragma unroll
            for (int rq = 0; rq < 4; ++rq) {
                float4 bq = *(const float4*)&b1[nt * 32 + rq * 8 + 4 * hh];
                acc[rq * 4 + 0] = bq.x; acc[rq * 4 + 1] = bq.y;
                acc[rq * 4 + 2] = bq.z; acc[rq * 4 + 3] = bq.w;
            }
            const f16* ah = W1sT_hi + (size_t)(nt * 32 + lr) * 64 + 8 * hh;
            #pragma unroll
            for (int ks = 0; ks < 4; ++ks) {
                f16x8 Ah = *(const f16x8*)(ah + ks * 16);
                acc = __builtin_amdgcn_mfma_f32_32x32x16_f16(Ah, Bh[ks].v, acc, 0, 0, 0);
            }
            if (sg < S) {
                float* op = Ahist + (size_t)sg * 256 + nt * 32 + 4 * hh;
                #pragma unroll
                for (int rq = 0; rq < 4; ++rq) {
                    *(float4*)(op + rq * 8) = make_float4(
                        acc[rq * 4 + 0], acc[rq * 4 + 1], acc[rq * 4 + 2], acc[rq * 4 + 3]);
                }
            }
        }
    }
}

// ---------------------------------------------------------------------------
// K4: fused MLP, frag-exchange, 8 waves x 128 rows, 1 n-tile per wave.
// PRE=true: dispF pre-converted to f16 (no cvt on critical path); D-frags
// ping-pong prefetched 2 st-iterations ahead.
// ---------------------------------------------------------------------------
template <bool PRE>
__global__ __launch_bounds__(512, 4) void mlp5_kernel(
    const float* __restrict__ dispF, const f16* __restrict__ dispF16,
    const float* __restrict__ Ahist,
    const f16* __restrict__ W1bT_hi, const f16* __restrict__ W1bT_lo,
    const f16* __restrict__ W2T_hi, const f16* __restrict__ W2T_lo,
    const float* __restrict__ b2, const float* __restrict__ W3,
    const float* __restrict__ b3, float* __restrict__ u,
    int ND, int per, float inv_per)
{
    __shared__ uint4 frag[4][16][64];   // 64KB frag-exchange buffer

    const int tid = threadIdx.x;
    const int w = tid >> 6, l = tid & 63, lr = l & 31, hh = l >> 5;
    const int RB = blockIdx.x * 128;
    const int nt = w;                    // wave's n-tile (0..7)

    // hoisted layer-1 A-frags
    const f16* a1h = W1bT_hi + (size_t)(nt * 32 + lr) * 64 + 8 * hh;
    const f16* a1l = W1bT_lo + (size_t)(nt * 32 + lr) * 64 + 8 * hh;
    f16x8 A1h[4], A1l[4];
    #pragma unroll
    for (int ks = 0; ks < 4; ++ks) {
        A1h[ks] = *(const f16x8*)(a1h + ks * 16);
        A1l[ks] = *(const f16x8*)(a1l + ks * 16);
    }

    // per-st row / session indices
    int rgc[4], srow[4];
    #pragma unroll
    for (int st = 0; st < 4; ++st) {
        int rg = RB + st * 32 + lr;
        rgc[st] = rg <= ND - 1 ? rg : ND - 1;
        int sr = (int)((float)rgc[st] * inv_per);
        sr += ((sr + 1) * per <= rgc[st]) ? 1 : 0;
        srow[st] = sr;
    }

    // ---------------- Phase 1: layer 1, D ping-pong prefetch --------------
    f16x8 Db[2][4];
    #pragma unroll
    for (int ks = 0; ks < 4; ++ks) {
        if (PRE) {
            Db[0][ks] = *(const f16x8*)(dispF16 + (size_t)rgc[0] * 64 + ks * 16 + 8 * hh);
            Db[1][ks] = *(const f16x8*)(dispF16 + (size_t)rgc[1] * 64 + ks * 16 + 8 * hh);
        } else {
            #pragma unroll
            for (int b = 0; b < 2; ++b) {
                const float* dp = dispF + (size_t)rgc[b] * 64 + ks * 16 + 8 * hh;
                float4 x0 = *(const float4*)dp;
                float4 x1 = *(const float4*)(dp + 4);
                f16x8 d;
                d[0] = (f16)x0.x; d[1] = (f16)x0.y; d[2] = (f16)x0.z; d[3] = (f16)x0.w;
                d[4] = (f16)x1.x; d[5] = (f16)x1.y; d[6] = (f16)x1.z; d[7] = (f16)x1.w;
                Db[b][ks] = d;
            }
        }
    }

    #pragma unroll
    for (int st = 0; st < 4; ++st) {
        const float* ap = Ahist + (size_t)srow[st] * 256;
        f32x16 acc;
        #pragma unroll
        for (int rq = 0; rq < 4; ++rq) {
            float4 av = *(const float4*)&ap[nt * 32 + rq * 8 + 4 * hh];
            acc[rq * 4 + 0] = av.x; acc[rq * 4 + 1] = av.y;
            acc[rq * 4 + 2] = av.z; acc[rq * 4 + 3] = av.w;
        }
        #pragma unroll
        for (int ks = 0; ks < 4; ++ks) {
            acc = __builtin_amdgcn_mfma_f32_32x32x16_f16(A1h[ks], Db[st & 1][ks], acc, 0, 0, 0);
            acc = __builtin_amdgcn_mfma_f32_32x32x16_f16(A1l[ks], Db[st & 1][ks], acc, 0, 0, 0);
        }
        // prefetch st+2 into the slot just consumed
        if (st + 2 < 4) {
            #pragma unroll
            for (int ks = 0; ks < 4; ++ks) {
                if (PRE) {
                    Db[st & 1][ks] = *(const f16x8*)(dispF16 + (size_t)rgc[st + 2] * 64 + ks * 16 + 8 * hh);
                } else {
                    const float* dp = dispF + (size_t)rgc[st + 2] * 64 + ks * 16 + 8 * hh;
                    float4 x0 = *(const float4*)dp;
                    float4 x1 = *(const float4*)(dp + 4);
                    f16x8 d;
                    d[0] = (f16)x0.x; d[1] = (f16)x0.y; d[2] = (f16)x0.z; d[3] = (f16)x0.w;
                    d[4] = (f16)x1.x; d[5] = (f16)x1.y; d[6] = (f16)x1.z; d[7] = (f16)x1.w;
                    Db[st & 1][ks] = d;
                }
            }
        }

        // elu + f16 pack (pairs along n1) + half-exchange -> layer-2 B-frags
        uint p[4][2];
        #pragma unroll
        for (int rq = 0; rq < 4; ++rq) {
            #pragma unroll
            for (int jj = 0; jj < 2; ++jj) {
                float a = elu_f(acc[rq * 4 + 2 * jj]);
                float b = elu_f(acc[rq * 4 + 2 * jj + 1]);
                f16x2 hp; hp[0] = (f16)a; hp[1] = (f16)b;
                p[rq][jj] = __builtin_bit_cast(uint, hp);
            }
        }
        #pragma unroll
        for (int c = 0; c < 2; ++c) {
            uint s0 = hh ? p[2 * c][0] : p[2 * c + 1][0];
            uint s1 = hh ? p[2 * c][1] : p[2 * c + 1][1];
            uint r0 = __shfl_xor(s0, 32, 64);
            uint r1 = __shfl_xor(s1, 32, 64);
            uint4 B;
            B.x = hh ? r0 : p[2 * c][0];
            B.y = hh ? r1 : p[2 * c][1];
            B.z = hh ? p[2 * c + 1][0] : r0;
            B.w = hh ? p[2 * c + 1][1] : r1;
            frag[st][2 * nt + c][l] = B;
        }
    }
    __syncthreads();

    // ---------------- Phase 2: layer 2 (wave's 32 n2 cols, all 128 rows) --
    f32x16 acc2[4];
    #pragma unroll
    for (int rq = 0; rq < 4; ++rq) {
        float4 bq = *(const float4*)&b2[nt * 32 + rq * 8 + 4 * hh];
        #pragma unroll
        for (int st = 0; st < 4; ++st) {
            acc2[st][rq * 4 + 0] = bq.x; acc2[st][rq * 4 + 1] = bq.y;
            acc2[st][rq * 4 + 2] = bq.z; acc2[st][rq * 4 + 3] = bq.w;
        }
    }
    const f16* w2h = W2T_hi + (size_t)(nt * 32 + lr) * 256 + 8 * hh;
    const f16* w2l = W2T_lo + (size_t)(nt * 32 + lr) * 256 + 8 * hh;

    #pragma unroll 4
    for (int kt = 0; kt < 16; ++kt) {
        f16x8 Ah = *(const f16x8*)(w2h + kt * 16);
        f16x8 Al = *(const f16x8*)(w2l + kt * 16);
        #pragma unroll
        for (int st = 0; st < 4; ++st) {
            F16x8U B; B.q = frag[st][kt][l];
            acc2[st] = __builtin_amdgcn_mfma_f32_32x32x16_f16(Ah, B.v, acc2[st], 0, 0, 0);
            acc2[st] = __builtin_amdgcn_mfma_f32_32x32x16_f16(Al, B.v, acc2[st], 0, 0, 0);
        }
    }

    // ---------------- Phase 3: layer-3 fold + cross-wave reduce ------------
    float up[4] = {0.f, 0.f, 0.f, 0.f};
    #pragma unroll
    for (int rq = 0; rq < 4; ++rq) {
        float4 wq = *(const float4*)&W3[nt * 32 + rq * 8 + 4 * hh];
        #pragma unroll
        for (int st = 0; st < 4; ++st) {
            up[st] += elu_f(acc2[st][rq * 4 + 0]) * wq.x
                    + elu_f(acc2[st][rq * 4 + 1]) * wq.y
                    + elu_f(acc2[st][rq * 4 + 2]) * wq.z
                    + elu_f(acc2[st][rq * 4 + 3]) * wq.w;
        }
    }
    #pragma unroll
    for (int st = 0; st < 4; ++st) up[st] += __shfl_xor(up[st], 32, 64);

    __syncthreads();   // frag reads done; reuse LDS as reduce buffer
    float* pb = (float*)frag;
    if (hh == 0) {
        #pragma unroll
        for (int st = 0; st < 4; ++st) pb[(w * 4 + st) * 32 + lr] = up[st];
    }
    __syncthreads();
    if (tid < 128) {
        int st = tid >> 5, lrr = tid & 31;
        float v = 0.f;
        #pragma unroll
        for (int w2 = 0; w2 < 8; ++w2) v += pb[(w2 * 4 + st) * 32 + lrr];
        int rg = RB + tid;
        if (rg < ND) u[rg] = v + b3[0];
    }
}

// ---------------------------------------------------------------------------
// K5: per-session loss + argmax/top-2 precision counts
// ---------------------------------------------------------------------------
template <int PER>
__global__ void session_kernel(const float* __restrict__ u, const int* __restrict__ clickSub,
                               const int* __restrict__ clickIdx, const int* __restrict__ dispIdx,
                               float* __restrict__ pLoss, int* __restrict__ pP1,
                               int* __restrict__ pP2, int S) {
    int s = blockIdx.x * blockDim.x + threadIdx.x;
    float lossv = 0.f; int p1 = 0, p2 = 0;
    if (s < S) {
        int base = s * PER;
        float ev[PER]; int it[PER];
        float sum_exp = 0.f;
        #pragma unroll
        for (int i = 0; i < PER; ++i) {
            float uu = u[base + i];
            ev[i] = expf(uu);
            sum_exp += ev[i];
            it[i] = dispIdx[(size_t)(base + i) * 2 + 1];
        }
        int crow = clickSub[s];
        lossv = -u[crow] + logf(sum_exp + 1.f);

        float bestv = -1.f; int besti = 0x7FFFFFFF;
        float secv = -1.f;  int seci = 0x7FFFFFFF;
        int ndist = 0;
        #pragma unroll
        for (int i = 0; i < PER; ++i) {
            bool first = true; float tot = 0.f;
            #pragma unroll
            for (int j = 0; j < PER; ++j) {
                if (it[j] == it[i]) { tot += ev[j]; if (j < i) first = false; }
            }
            if (first) {
                ndist++;
                if (tot > bestv || (tot == bestv && it[i] < besti)) {
                    secv = bestv; seci = besti;
                    bestv = tot;  besti = it[i];
                } else if (tot > secv || (tot == secv && it[i] < seci)) {
                    secv = tot; seci = it[i];
                }
            }
        }
        if (ndist < 2) seci = (besti == 0) ? 1 : 0;
        int citem = clickIdx[s * 2 + 1];
        p1 = (citem == besti) ? 1 : 0;
        p2 = (citem == besti || citem == seci) ? 1 : 0;
    }
    __shared__ float rf[TPB]; __shared__ int r1[TPB]; __shared__ int r2[TPB];
    int t = threadIdx.x;
    rf[t] = lossv; r1[t] = p1; r2[t] = p2;
    __syncthreads();
    for (int off = TPB / 2; off > 0; off >>= 1) {
        if (t < off) { rf[t] += rf[t + off]; r1[t] += r1[t + off]; r2[t] += r2[t + off]; }
        __syncthreads();
    }
    if (t == 0) { pLoss[blockIdx.x] = rf[0]; pP1[blockIdx.x] = r1[0]; pP2[blockIdx.x] = r2[0]; }
}

// ---------------------------------------------------------------------------
// K6: reduce block partials, emit the 7 scalar outputs.
// ---------------------------------------------------------------------------
__global__ void finalize_kernel(const float* __restrict__ pLoss, const int* __restrict__ pP1,
                                const int* __restrict__ pP2, int nb, float event_cnt,
                                float* __restrict__ out) {
    __shared__ float sf[TPB]; __shared__ int s1[TPB]; __shared__ int s2[TPB];
    int t = threadIdx.x;
    float lf = 0.f; int a1 = 0, a2 = 0;
    for (int i = t; i < nb; i += TPB) { lf += pLoss[i]; a1 += pP1[i]; a2 += pP2[i]; }
    sf[t] = lf; s1[t] = a1; s2[t] = a2;
    __syncthreads();
    for (int off = TPB / 2; off > 0; off >>= 1) {
        if (t < off) { sf[t] += sf[t + off]; s1[t] += s1[t + off]; s2[t] += s2[t + off]; }
        __syncthreads();
    }
    if (t == 0) {
        float ls = sf[0];
        float p1 = (float)s1[0];
        float p2 = (float)s2[0];
        out[0] = ls / event_cnt;
        out[1] = p1 / event_cnt;
        out[2] = p2 / event_cnt;
        out[3] = ls;
        out[4] = p1;
        out[5] = p2;
        out[6] = event_cnt;
    }
}

// ---------------------------------------------------------------------------
extern "C" void kernel_launch(void* const* d_in, const int* in_sizes, int n_in,
                              void* d_out, int out_size, void* d_ws, size_t ws_size,
                              hipStream_t stream) {
    const float* dispF    = (const float*)d_in[0];
    const float* Xs       = (const float*)d_in[1];
    const float* W1       = (const float*)d_in[2];
    const float* b1       = (const float*)d_in[3];
    const float* W2       = (const float*)d_in[4];
    const float* b2       = (const float*)d_in[5];
    const float* W3       = (const float*)d_in[6];
    const float* b3       = (const float*)d_in[7];
    const int*   tril     = (const int*)d_in[8];
    const int*   clickSub = (const int*)d_in[11];
    const int*   clickIdx = (const int*)d_in[12];
    const int*   dispIdx  = (const int*)d_in[13];

    const int S    = in_sizes[11];
    const int ND   = in_sizes[10];
    const int F    = in_sizes[1] / S;            // 64
    const int H    = in_sizes[3];                // 256
    const int NT   = in_sizes[9];
    const int BAND = NT / S;                     // 20
    const int PW   = in_sizes[2] / (F * H) - 1;  // 10
    const int per  = ND / S;                     // 10

    float* ws    = (float*)d_ws;
    float* hist  = ws;                                   // S*F
    float* Ahist = hist + (size_t)S * F;                 // S*H
    float* u     = Ahist + (size_t)S * H;                // ND (+pad)
    const int nb5 = (S + TPB - 1) / TPB;
    float* pLoss = u + ((size_t)ND + 128);               // nb5
    int*   pP1   = (int*)(pLoss + nb5);
    int*   pP2   = pP1 + nb5;
    size_t f32_used = (size_t)(pP2 + nb5 - (int*)ws);
    f32_used = (f32_used + 3) & ~(size_t)3;              // 16B align
    f16* W1bT_hi = (f16*)(ws + f32_used);                // 256*64
    f16* W1bT_lo = W1bT_hi + 16384;
    f16* W1sT_hi = W1bT_lo + 16384;                      // 256*64
    f16* W2T_hi  = W1sT_hi + 16384;                      // 256*256
    f16* W2T_lo  = W2T_hi + 65536;
    f16* dispF16 = W2T_lo + 65536;                       // ND*64 (optional)

    size_t need_bytes = ((char*)(dispF16 + (size_t)ND * 64)) - (char*)d_ws;
    const bool PRE = ws_size >= need_bytes;

    hist_kernel<<<(S * F + TPB - 1) / TPB, TPB, 0, stream>>>(Xs, tril, hist, S, BAND, F);
    prep_kernel<<<384, TPB, 0, stream>>>(W1, W2, PW, W1bT_hi, W1bT_lo, W1sT_hi, W2T_hi, W2T_lo);
    if (PRE) {
        dispf16_kernel<<<2048, TPB, 0, stream>>>(dispF, dispF16, ND * 8);
    }
    ahist_mfma_kernel<<<(S + 127) / 128, TPB, 0, stream>>>(hist, W1sT_hi, b1, Ahist, S);
    if (PRE) {
        mlp5_kernel<true><<<(ND + 127) / 128, 512, 0, stream>>>(
            dispF, dispF16, Ahist, W1bT_hi, W1bT_lo, W2T_hi, W2T_lo, b2, W3, b3, u,
            ND, per, 1.0f / (float)per);
    } else {
        mlp5_kernel<false><<<(ND + 127) / 128, 512, 0, stream>>>(
            dispF, dispF16, Ahist, W1bT_hi, W1bT_lo, W2T_hi, W2T_lo, b2, W3, b3, u,
            ND, per, 1.0f / (float)per);
    }
    session_kernel<10><<<nb5, TPB, 0, stream>>>(u, clickSub, clickIdx, dispIdx, pLoss, pP1, pP2, S);
    finalize_kernel<<<1, TPB, 0, stream>>>(pLoss, pP1, pP2, nb5, (float)S, (float*)d_out);
}